// Round 6
// baseline (1114.914 us; speedup 1.0000x reference)
//
#include <hip/hip_runtime.h>

#define N_IN   128
#define N_HID  15
#define N_HIDP 16
#define N_OUT  32
#define NSEG   16

// ---------------------------------------------------------------------------
// Detect int64 vs int32 edge payload: if int64, every odd 32-bit word (high
// word of a value < 2^31) is 0.
// ---------------------------------------------------------------------------
__global__ void detect_kernel(const int* __restrict__ idx, int* __restrict__ flag) {
    __shared__ int nz;
    if (threadIdx.x == 0) nz = 0;
    __syncthreads();
    if (idx[2 * threadIdx.x + 1] != 0) atomicOr(&nz, 1);
    __syncthreads();
    if (threadIdx.x == 0) *flag = (nz == 0) ? 1 : 0;
}

// ---------------------------------------------------------------------------
// Convert idx -> int32 arrays + 16-way segmented in-degree histogram.
// Segmenting spreads the 6.4M atomics over 16x the lines -> 16x less word
// contention at the coherence point.
// ---------------------------------------------------------------------------
__global__ void convert_deg_kernel(const void* __restrict__ idx, int E,
                                   const int* __restrict__ flag,
                                   int* __restrict__ src32, int* __restrict__ dst32,
                                   unsigned* __restrict__ deg_seg, int N) {
    int e = blockIdx.x * 256 + threadIdx.x;
    if (e >= E) return;
    int s, d;
    if (*flag) {
        const long long* p = (const long long*)idx;
        s = (int)p[e];
        d = (int)p[E + e];
    } else {
        const int* p = (const int*)idx;
        s = p[e];
        d = p[E + e];
    }
    src32[e] = s;
    dst32[e] = d;
    atomicAdd(&deg_seg[(size_t)(blockIdx.x & (NSEG - 1)) * N + d], 1u);
}

// dinv[i] = rsqrt(sum of segments + 1)
__global__ void dinv_kernel(const unsigned* __restrict__ deg_seg,
                            float* __restrict__ dinv, int N) {
    int i = blockIdx.x * 256 + threadIdx.x;
    if (i >= N) return;
    unsigned deg = 0;
#pragma unroll
    for (int s = 0; s < NSEG; ++s) deg += deg_seg[(size_t)s * N + i];
    dinv[i] = rsqrtf((float)deg + 1.0f);  // +1 = self-loop
}

// ---------------------------------------------------------------------------
// GEMM1: hs[i][c] = (x[i] @ W1[:,c]) * dinv[i], padded to 16 ch (ch15 = 0).
// ---------------------------------------------------------------------------
__global__ __launch_bounds__(256) void gemm1_kernel(
    const float* __restrict__ x, const float* __restrict__ W1,
    const float* __restrict__ dinv, float* __restrict__ hs, int N) {
    __shared__ float Wl[N_IN * N_HIDP];
    for (int i = threadIdx.x; i < N_IN * N_HIDP; i += 256) {
        int k = i >> 4, c = i & 15;
        Wl[i] = (c < N_HID) ? W1[k * N_HID + c] : 0.f;
    }
    __syncthreads();
    const float4* __restrict__ Wl4 = (const float4*)Wl;
    const float4* __restrict__ x4  = (const float4*)x;

    int r0 = blockIdx.x * 512 + threadIdx.x;
    int r1 = r0 + 256;
    int r0c = r0 < N ? r0 : N - 1;
    int r1c = r1 < N ? r1 : N - 1;

    float acc0[16], acc1[16];
#pragma unroll
    for (int c = 0; c < 16; ++c) { acc0[c] = 0.f; acc1[c] = 0.f; }

    for (int k4 = 0; k4 < 32; ++k4) {
        float4 xv0 = x4[r0c * 32 + k4];
        float4 xv1 = x4[r1c * 32 + k4];
        float xs0[4] = {xv0.x, xv0.y, xv0.z, xv0.w};
        float xs1[4] = {xv1.x, xv1.y, xv1.z, xv1.w};
#pragma unroll
        for (int t = 0; t < 4; ++t) {
            int k = k4 * 4 + t;
            float4 wa = Wl4[k * 4 + 0];
            float4 wb = Wl4[k * 4 + 1];
            float4 wc = Wl4[k * 4 + 2];
            float4 wd = Wl4[k * 4 + 3];
            float wf[16] = {wa.x, wa.y, wa.z, wa.w, wb.x, wb.y, wb.z, wb.w,
                            wc.x, wc.y, wc.z, wc.w, wd.x, wd.y, wd.z, wd.w};
#pragma unroll
            for (int c = 0; c < 16; ++c) {
                acc0[c] = fmaf(xs0[t], wf[c], acc0[c]);
                acc1[c] = fmaf(xs1[t], wf[c], acc1[c]);
            }
        }
    }
    float4* __restrict__ hs4 = (float4*)hs;
    if (r0 < N) {
        float di = dinv[r0];
#pragma unroll
        for (int j = 0; j < 4; ++j)
            hs4[r0 * 4 + j] = make_float4(acc0[4*j]*di, acc0[4*j+1]*di,
                                          acc0[4*j+2]*di, acc0[4*j+3]*di);
    }
    if (r1 < N) {
        float di = dinv[r1];
#pragma unroll
        for (int j = 0; j < 4; ++j)
            hs4[r1 * 4 + j] = make_float4(acc1[4*j]*di, acc1[4*j+1]*di,
                                          acc1[4*j+2]*di, acc1[4*j+3]*di);
    }
}

// ---------------------------------------------------------------------------
// Scatter: 16 lanes per edge (c = lane&15), 4 edges per thread. All 4 gathers
// issued before the 4 fire-and-forget atomics so 4 random lines stay in
// flight per lane. Zero messages skipped (pad lane + layer-2 ReLU zeros).
// ---------------------------------------------------------------------------
__global__ __launch_bounds__(256) void scatter_kernel(
    const int* __restrict__ src, const int* __restrict__ dst, int E,
    const float* __restrict__ feat, float* __restrict__ agg) {
    const int c = threadIdx.x & 15;
    const long long G  = (long long)blockIdx.x * 16 + (threadIdx.x >> 4);
    const long long NG = (long long)gridDim.x * 16;

    int s[4], d[4];
    bool ok[4];
#pragma unroll
    for (int k = 0; k < 4; ++k) {
        long long e = (long long)k * NG + G;
        ok[k] = (e < E);
        long long ec = ok[k] ? e : 0;
        s[k] = src[ec];
        d[k] = dst[ec];
    }
    float v[4];
#pragma unroll
    for (int k = 0; k < 4; ++k)
        v[k] = feat[(size_t)s[k] * N_HIDP + c];
#pragma unroll
    for (int k = 0; k < 4; ++k)
        if (ok[k] && v[k] != 0.f)
            atomicAdd(&agg[(size_t)d[k] * N_HIDP + c], v[k]);
}

// finalize1: hs2[i][c] = relu(dinv*(agg+hs_self) + b1) * dinv  (pad ch -> 0)
__global__ void finalize1_kernel(const float* __restrict__ agg,
                                 const float* __restrict__ hs,
                                 const float* __restrict__ dinv,
                                 const float* __restrict__ b1,
                                 float* __restrict__ hs2, int N) {
    int t = blockIdx.x * 256 + threadIdx.x;
    int i = t >> 4, c = t & 15;
    if (i >= N) return;
    float di = dinv[i];
    float sum = agg[(size_t)i * N_HIDP + c] + hs[(size_t)i * N_HIDP + c];
    float b = (c < N_HID) ? b1[c] : 0.f;
    float v = fmaxf(di * sum + b, 0.f);
    hs2[(size_t)i * N_HIDP + c] = v * di;
}

// finalize2: out[i] = (dinv*(agg+hs2_self)) @ W2 + b2, LDS-staged u.
__global__ __launch_bounds__(256) void finalize2_kernel(
    const float* __restrict__ agg, const float* __restrict__ hs2,
    const float* __restrict__ dinv, const float* __restrict__ W2,
    const float* __restrict__ b2, float* __restrict__ out, int N) {
    __shared__ float W2l[N_HIDP * N_OUT];
    __shared__ float ubuf[16][17];
    for (int t = threadIdx.x; t < N_HIDP * N_OUT; t += 256)
        W2l[t] = (t < N_HID * N_OUT) ? W2[t] : 0.f;

    int c = threadIdx.x & 15, q = threadIdx.x >> 4;
    int i = blockIdx.x * 16 + q;
    int iw = i < N ? i : N - 1;
    float di = dinv[iw];
    ubuf[q][c] = di * (agg[(size_t)iw * N_HIDP + c] + hs2[(size_t)iw * N_HIDP + c]);
    __syncthreads();

    float a0 = b2[c], a1 = b2[c + 16];
#pragma unroll
    for (int k = 0; k < N_HID; ++k) {
        float uv = ubuf[q][k];
        a0 = fmaf(uv, W2l[k * N_OUT + c], a0);
        a1 = fmaf(uv, W2l[k * N_OUT + c + 16], a1);
    }
    if (i < N) {
        out[(size_t)i * N_OUT + c] = a0;
        out[(size_t)i * N_OUT + c + 16] = a1;
    }
}

// ---------------------------------------------------------------------------
extern "C" void kernel_launch(void* const* d_in, const int* in_sizes, int n_in,
                              void* d_out, int out_size, void* d_ws, size_t ws_size,
                              hipStream_t stream) {
    const float* x   = (const float*)d_in[0];
    const void*  eix = d_in[1];
    const float* W1  = (const float*)d_in[2];
    const float* b1  = (const float*)d_in[3];
    const float* W2  = (const float*)d_in[4];
    const float* b2  = (const float*)d_in[5];
    float* out = (float*)d_out;

    const int N = in_sizes[0] / N_IN;   // 200000
    const int E = in_sizes[1] / 2;      // 6400000

    char* ws = (char*)d_ws;
    size_t off = 0;
    auto alloc = [&](size_t bytes) -> void* {
        void* p = ws + off;
        off += (bytes + 255) & ~(size_t)255;
        return p;
    };
    int*      src32   = (int*)alloc((size_t)E * 4);
    int*      dst32   = (int*)alloc((size_t)E * 4);
    unsigned* deg_seg = (unsigned*)alloc((size_t)NSEG * N * 4);  // 12.8 MB
    float*    dinv    = (float*)alloc((size_t)N * 4);
    float*    hs      = (float*)alloc((size_t)N * N_HIDP * 4);
    float*    hs2     = (float*)alloc((size_t)N * N_HIDP * 4);
    float*    agg     = (float*)alloc((size_t)N * N_HIDP * 4);
    int*      flag    = (int*)alloc(256);

    hipMemsetAsync(deg_seg, 0, (size_t)NSEG * N * 4, stream);
    hipMemsetAsync(agg, 0, (size_t)N * N_HIDP * 4, stream);

    detect_kernel<<<1, 256, 0, stream>>>((const int*)eix, flag);
    convert_deg_kernel<<<(E + 255) / 256, 256, 0, stream>>>(eix, E, flag, src32, dst32, deg_seg, N);
    dinv_kernel<<<(N + 255) / 256, 256, 0, stream>>>(deg_seg, dinv, N);
    gemm1_kernel<<<(N + 511) / 512, 256, 0, stream>>>(x, W1, dinv, hs, N);

    const int sblocks = (E + 63) / 64;   // 4 edges/thread, 16 lanes/edge
    scatter_kernel<<<sblocks, 256, 0, stream>>>(src32, dst32, E, hs, agg);
    finalize1_kernel<<<(N * 16 + 255) / 256, 256, 0, stream>>>(agg, hs, dinv, b1, hs2, N);

    hipMemsetAsync(agg, 0, (size_t)N * N_HIDP * 4, stream);
    scatter_kernel<<<sblocks, 256, 0, stream>>>(src32, dst32, E, hs2, agg);
    finalize2_kernel<<<(N + 15) / 16, 256, 0, stream>>>(agg, hs2, dinv, W2, b2, out, N);
}